// Round 7
// baseline (371.258 us; speedup 1.0000x reference)
//
#include <hip/hip_runtime.h>
#include <hip/hip_bf16.h>

// Problem constants: B=4, C_IN=C_OUT=64, N=100000, K=6
#define BB   4
#define NN   100000
#define TOT  (BB * NN)          // 400000
#define KK   6
#define EPSV 1e-5f

using bf16   = __hip_bfloat16;
using ushort = unsigned short;
using uint32 = unsigned int;
typedef __attribute__((ext_vector_type(8))) short  short8;   // 8 bf16 = 4 VGPRs
typedef __attribute__((ext_vector_type(4))) float  float4v;  // MFMA C/D

union U4S8 { uint4 u; short8 s; };

__device__ __forceinline__ unsigned f2bu(float f) {          // f32 -> raw bf16 RNE
    union { bf16 h; ushort u; } c; c.h = __float2bfloat16(f); return c.u;
}
__device__ __forceinline__ unsigned pk(float a, float b) {
    return f2bu(a) | (f2bu(b) << 16);
}
__device__ __forceinline__ float blo(unsigned x) {           // low bf16 -> f32
    union { unsigned u; float f; } c; c.u = x << 16; return c.f;
}
__device__ __forceinline__ float bhi(unsigned x) {           // high bf16 -> f32
    union { unsigned u; float f; } c; c.u = x & 0xFFFF0000u; return c.f;
}
__device__ __forceinline__ unsigned relu2(unsigned x) {      // relu on packed 2xbf16
    unsigned lo = (unsigned)(((int)(x << 16)) >> 31) & 0x0000FFFFu;
    unsigned hi = ((unsigned)(((int)x) >> 31)) << 16;
    return x & ~(lo | hi);
}
__device__ __forceinline__ int batch_base(int g) {           // (g/NN)*NN via compares
    return (g >= 3 * NN) ? 3 * NN : (g >= 2 * NN) ? 2 * NN : (g >= NN) ? NN : 0;
}

#define ACC8(v)  { h[0]+=blo(v.x); h[1]+=bhi(v.x); h[2]+=blo(v.y); h[3]+=bhi(v.y); \
                   h[4]+=blo(v.z); h[5]+=bhi(v.z); h[6]+=blo(v.w); h[7]+=bhi(v.w); }
#define ACCR8(v) { unsigned a0=relu2(v.x),a1=relu2(v.y),a2=relu2(v.z),a3=relu2(v.w); \
                   h[0]+=blo(a0); h[1]+=bhi(a0); h[2]+=blo(a1); h[3]+=bhi(a1); \
                   h[4]+=blo(a2); h[5]+=bhi(a2); h[6]+=blo(a3); h[7]+=bhi(a3); }

// ---------------------------------------------------------------------------
// wprep0: swizzle stacked weights [We | Wo] (K=128) into MFMA A-role frags.
// Wf0[((t*4+ks)*64+lane)*8+i] = Wstack[o=t*16+(lane&15)][c=ks*32+(lane>>4)*8+i]
// where Wstack[o][c] = W0[o][c&63][c>>6]  (c<64 -> We=W0[..][0], else Wo).
// ---------------------------------------------------------------------------
__global__ void wprep0_k(const float* __restrict__ W0, ushort* __restrict__ Wf0)
{
    int L = blockIdx.x * 256 + threadIdx.x;        // 8192
    if (L < 8192) {
        int i = L & 7, lane = (L >> 3) & 63, r = L >> 9;   // r = t*4+ks
        int t = r >> 2, ks = r & 3;
        int o = t * 16 + (lane & 15);
        int c = ks * 32 + (lane >> 4) * 8 + i;             // stacked 0..127
        Wf0[L] = f2bu(W0[o * 128 + (c & 63) * 2 + (c >> 6)]);
    }
}

// ---------------------------------------------------------------------------
// xpose: x [B,C,N] f32 -> xT [B,N,C] bf16 (point-major 128-B rows).
// v2: pack bf16 pairs during the (coalesced) load phase into a uint tile
// [64][36] (row 144 B -> 16-B aligned b128 reads); store epilogue emits
// 1-KB wave transactions (8 points x 16 B/lane) instead of 64x128-B.
// Store instrs/block: 64 -> 8. LDS 16.9 -> 9.2 KB.
// ---------------------------------------------------------------------------
__global__ __launch_bounds__(256) void xpose_k(const float* __restrict__ x,
                                               ushort* __restrict__ xT)
{
    __shared__ uint32 tileP[64][36];   // [point][packed ch-pair], pad to 36
    const int b  = blockIdx.y;
    const int n0 = blockIdx.x * 64;
    const int tx = threadIdx.x & 63;
    const int ty = threadIdx.x >> 6;
    const float* xb = x + (size_t)b * 64 * NN;
    const int n = n0 + tx;
    const bool valid = (n < NN);
#pragma unroll
    for (int cc = 0; cc < 64; cc += 8) {
        const int c = cc + ty * 2;                 // even channel
        float a0 = valid ? xb[(size_t)c * NN + n] : 0.f;        // 256-B coalesced
        float a1 = valid ? xb[(size_t)(c + 1) * NN + n] : 0.f;  // 256-B coalesced
        tileP[tx][c >> 1] = pk(a0, a1);
    }
    __syncthreads();
    // epilogue: thread -> (point p, 16-B chunk s); wave = 8 pts x 8 chunks = 1 KB
    const int s  = threadIdx.x & 7;
    const int p0 = threadIdx.x >> 3;               // 0..31
#pragma unroll
    for (int t = 0; t < 2; ++t) {
        const int p  = p0 + t * 32;
        const int n2 = n0 + p;
        if (n2 < NN) {
            uint4 v = *(const uint4*)(&tileP[p][s * 4]);        // b128, aligned
            *(uint4*)(xT + ((size_t)b * NN + n2) * 64 + s * 8) = v;
        }
    }
}

// ---------------------------------------------------------------------------
// gatherx: SX[g] = sum_k xT[nb_k]  (gather-BEFORE-GEMM restructure).
// 8 lanes/point (p=lane>>3, 16-B chunk s=lane&7); per point 6 gathered uint4.
// ---------------------------------------------------------------------------
__global__ __launch_bounds__(256, 4) void gatherx_k(
    const ushort* __restrict__ xT, const int* __restrict__ neigh,
    ushort* __restrict__ SX)
{
    const int wave = threadIdx.x >> 6;
    const int lane = threadIdx.x & 63;
    const int p    = lane >> 3;
    const int s    = lane & 7;
    const int so   = s * 8;
    const int g0   = (blockIdx.x * 4 + wave) * 32;   // 3125 blocks * 128 = TOT

#pragma unroll
    for (int t = 0; t < 4; ++t) {
        const int gme = g0 + t * 8 + p;
        const int bo  = batch_base(gme);
        const int* np = neigh + (size_t)gme * 6;
        const uint2 i01 = *(const uint2*)(np);
        const uint2 i23 = *(const uint2*)(np + 2);
        const uint2 i45 = *(const uint2*)(np + 4);

        uint4 v0 = *(const uint4*)(xT + (size_t)(bo + (int)i01.x) * 64 + so);
        uint4 v1 = *(const uint4*)(xT + (size_t)(bo + (int)i01.y) * 64 + so);
        uint4 v2 = *(const uint4*)(xT + (size_t)(bo + (int)i23.x) * 64 + so);
        uint4 v3 = *(const uint4*)(xT + (size_t)(bo + (int)i23.y) * 64 + so);
        uint4 v4 = *(const uint4*)(xT + (size_t)(bo + (int)i45.x) * 64 + so);
        uint4 v5 = *(const uint4*)(xT + (size_t)(bo + (int)i45.y) * 64 + so);

        float h[8] = {0, 0, 0, 0, 0, 0, 0, 0};
        ACC8(v0) ACC8(v1) ACC8(v2) ACC8(v3) ACC8(v4) ACC8(v5)

        uint4 st;
        st.x = pk(h[0], h[1]); st.y = pk(h[2], h[3]);
        st.z = pk(h[4], h[5]); st.w = pk(h[6], h[7]);
        *(uint4*)(SX + (size_t)gme * 64 + so) = st;
    }
}

// ---------------------------------------------------------------------------
// GEMM1 (K=128): h[g] = [xT[g] ; SX[g]] · [We;Wo]  -> hT bf16 (raw h).
// BN stats (sum, sumsq of relu(h)) fused in the f32-accumulator epilogue.
// ---------------------------------------------------------------------------
__global__ __launch_bounds__(256, 3) void gemm1_k(
    const ushort* __restrict__ xT, const ushort* __restrict__ SX,
    const ushort* __restrict__ Wf, ushort* __restrict__ hT,
    float* __restrict__ stats)
{
    __shared__ float red[4][128];
    const int wave = threadIdx.x >> 6;
    const int lane = threadIdx.x & 63;
    const int col  = lane & 15;
    const int quad = lane >> 4;

    short8 wf[4][4];
#pragma unroll
    for (int t = 0; t < 4; ++t)
#pragma unroll
        for (int ks = 0; ks < 4; ++ks)
            wf[t][ks] = *(const short8*)(Wf + ((t * 4 + ks) * 64 + lane) * 8);

    float sA[16], sB[16];
#pragma unroll
    for (int j = 0; j < 16; ++j) { sA[j] = 0.f; sB[j] = 0.f; }

    const int wid = blockIdx.x * 4 + wave;            // 2500 waves, 10 tiles each
    for (int tile = wid; tile < 25000; tile += 2500) {
        const size_t g0 = (size_t)tile * 16;
        const ushort* xr = xT + (g0 + col) * 64 + quad * 8;
        const ushort* sr = SX + (g0 + col) * 64 + quad * 8;
        short8 p0 = *(const short8*)(xr);
        short8 p1 = *(const short8*)(xr + 32);
        short8 p2 = *(const short8*)(sr);
        short8 p3 = *(const short8*)(sr + 32);

        float4v acc[4];
#pragma unroll
        for (int t = 0; t < 4; ++t) acc[t] = (float4v){0.f, 0.f, 0.f, 0.f};
#pragma unroll
        for (int t = 0; t < 4; ++t)
            acc[t] = __builtin_amdgcn_mfma_f32_16x16x32_bf16(wf[t][0], p0, acc[t], 0, 0, 0);
#pragma unroll
        for (int t = 0; t < 4; ++t)
            acc[t] = __builtin_amdgcn_mfma_f32_16x16x32_bf16(wf[t][1], p1, acc[t], 0, 0, 0);
#pragma unroll
        for (int t = 0; t < 4; ++t)
            acc[t] = __builtin_amdgcn_mfma_f32_16x16x32_bf16(wf[t][2], p2, acc[t], 0, 0, 0);
#pragma unroll
        for (int t = 0; t < 4; ++t)
            acc[t] = __builtin_amdgcn_mfma_f32_16x16x32_bf16(wf[t][3], p3, acc[t], 0, 0, 0);

        // store raw h (bf16) + accumulate relu stats from f32 acc
#pragma unroll
        for (int t = 0; t < 4; ++t) {
            uint2 d;
            d.x = pk(acc[t][0], acc[t][1]);
            d.y = pk(acc[t][2], acc[t][3]);
            *(uint2*)(hT + (g0 + col) * 64 + t * 16 + quad * 4) = d;
#pragma unroll
            for (int r = 0; r < 4; ++r) {
                float rv = fmaxf(acc[t][r], 0.f);
                sA[t * 4 + r] += rv;
                sB[t * 4 + r]  = fmaf(rv, rv, sB[t * 4 + r]);
            }
        }
    }

    // reduce over the 16 point-cols (lane bits 0..3)
#pragma unroll
    for (int d = 1; d < 16; d <<= 1)
#pragma unroll
        for (int j = 0; j < 16; ++j) {
            sA[j] += __shfl_xor(sA[j], d);
            sB[j] += __shfl_xor(sB[j], d);
        }
    if (col == 0) {
#pragma unroll
        for (int t = 0; t < 4; ++t)
#pragma unroll
            for (int r = 0; r < 4; ++r) {
                const int o = t * 16 + quad * 4 + r;
                red[wave][o]      = sA[t * 4 + r];
                red[wave][64 + o] = sB[t * 4 + r];
            }
    }
    __syncthreads();
    if (threadIdx.x < 128) {
        float v = red[0][threadIdx.x] + red[1][threadIdx.x]
                + red[2][threadIdx.x] + red[3][threadIdx.x];
        atomicAdd(&stats[threadIdx.x], v);   // 625 adds per address total
    }
}

// ---------------------------------------------------------------------------
// bnA: stats -> per-channel affine  rhat = a*relu(h) + b.   (1 block, ~2 us)
// ---------------------------------------------------------------------------
__global__ void bnA_k(const float* __restrict__ stats, const float* __restrict__ gamma,
                      const float* __restrict__ beta, float* __restrict__ ab)
{
    const int o = threadIdx.x;
    if (o < 64) {
        const float inv = 1.f / (float)TOT;
        float mean = stats[o] * inv;
        float var  = stats[64 + o] * inv - mean * mean;   // biased var (jnp.var)
        float a    = gamma[o] * rsqrtf(var + EPSV);
        ab[o]      = a;
        ab[64 + o] = fmaf(-a, mean, beta[o]);
    }
}

// ---------------------------------------------------------------------------
// bnB: Wf1 = swizzled stacked [a⊙We1 | a⊙Wo1] (K=128, blocks 0..31) +
// bias[o] = sum_c b_c*(We1[o][c] + 6*Wo1[o][c])  (block 32).
// ---------------------------------------------------------------------------
__global__ __launch_bounds__(256) void bnB_k(
    const float* __restrict__ ab, const float* __restrict__ W1,
    ushort* __restrict__ Wf1, float* __restrict__ bias)
{
    if (blockIdx.x < 32) {
        int L = blockIdx.x * 256 + threadIdx.x;   // 8192
        int i = L & 7, lane = (L >> 3) & 63, r = L >> 9;
        int t = r >> 2, ks = r & 3;
        int o = t * 16 + (lane & 15);
        int c = ks * 32 + (lane >> 4) * 8 + i;
        int cc = c & 63;
        Wf1[L] = f2bu(ab[cc] * W1[o * 128 + cc * 2 + (c >> 6)]);
    } else if (threadIdx.x < 64) {
        const int o = threadIdx.x;
        float s = 0.f;
#pragma unroll
        for (int c = 0; c < 64; ++c)
            s += ab[64 + c] * (W1[o * 128 + c * 2] + 6.f * W1[o * 128 + c * 2 + 1]);
        bias[o] = s;
    }
}

// ---------------------------------------------------------------------------
// gatherh: SH[g] = sum_k relu(hT[nb_k])  (BN's a,b folded downstream).
// ---------------------------------------------------------------------------
__global__ __launch_bounds__(256, 4) void gatherh_k(
    const ushort* __restrict__ hT, const int* __restrict__ neigh,
    ushort* __restrict__ SH)
{
    const int wave = threadIdx.x >> 6;
    const int lane = threadIdx.x & 63;
    const int p    = lane >> 3;
    const int s    = lane & 7;
    const int so   = s * 8;
    const int g0   = (blockIdx.x * 4 + wave) * 32;

#pragma unroll
    for (int t = 0; t < 4; ++t) {
        const int gme = g0 + t * 8 + p;
        const int bo  = batch_base(gme);
        const int* np = neigh + (size_t)gme * 6;
        const uint2 i01 = *(const uint2*)(np);
        const uint2 i23 = *(const uint2*)(np + 2);
        const uint2 i45 = *(const uint2*)(np + 4);

        uint4 v0 = *(const uint4*)(hT + (size_t)(bo + (int)i01.x) * 64 + so);
        uint4 v1 = *(const uint4*)(hT + (size_t)(bo + (int)i01.y) * 64 + so);
        uint4 v2 = *(const uint4*)(hT + (size_t)(bo + (int)i23.x) * 64 + so);
        uint4 v3 = *(const uint4*)(hT + (size_t)(bo + (int)i23.y) * 64 + so);
        uint4 v4 = *(const uint4*)(hT + (size_t)(bo + (int)i45.x) * 64 + so);
        uint4 v5 = *(const uint4*)(hT + (size_t)(bo + (int)i45.y) * 64 + so);

        float h[8] = {0, 0, 0, 0, 0, 0, 0, 0};
        ACCR8(v0) ACCR8(v1) ACCR8(v2) ACCR8(v3) ACCR8(v4) ACCR8(v5)

        uint4 st;
        st.x = pk(h[0], h[1]); st.y = pk(h[2], h[3]);
        st.z = pk(h[4], h[5]); st.w = pk(h[6], h[7]);
        *(uint4*)(SH + (size_t)gme * 64 + so) = st;
    }
}

// ---------------------------------------------------------------------------
// GEMM2 (K=128): out = relu( [relu(h) ; SH]·Wf1 + bias + h ).
// ---------------------------------------------------------------------------
__global__ __launch_bounds__(256, 3) void gemm2_k(
    const ushort* __restrict__ hT, const ushort* __restrict__ SH,
    const ushort* __restrict__ Wf, const float* __restrict__ bias,
    float* __restrict__ out)
{
    __shared__ float ts[64][65];
    const int wave = threadIdx.x >> 6;
    const int lane = threadIdx.x & 63;
    const int col  = lane & 15;
    const int quad = lane >> 4;

    short8 wf[4][4];
#pragma unroll
    for (int t = 0; t < 4; ++t)
#pragma unroll
        for (int ks = 0; ks < 4; ++ks)
            wf[t][ks] = *(const short8*)(Wf + ((t * 4 + ks) * 64 + lane) * 8);

    float binit[16];
#pragma unroll
    for (int t = 0; t < 4; ++t)
#pragma unroll
        for (int r = 0; r < 4; ++r)
            binit[t * 4 + r] = bias[t * 16 + quad * 4 + r];

    for (int it = 0; it < 10; ++it) {
        const int gb = (blockIdx.x * 10 + it) * 64;       // 64 consecutive points
        const size_t g0 = (size_t)gb + wave * 16;
        const ushort* hr = hT + (g0 + col) * 64 + quad * 8;
        const ushort* sr = SH + (g0 + col) * 64 + quad * 8;
        U4S8 p0, p1, p2, p3;
        p0.u = *(const uint4*)(hr);
        p1.u = *(const uint4*)(hr + 32);
        p2.u = *(const uint4*)(sr);
        p3.u = *(const uint4*)(sr + 32);
        p0.u.x = relu2(p0.u.x); p0.u.y = relu2(p0.u.y);
        p0.u.z = relu2(p0.u.z); p0.u.w = relu2(p0.u.w);
        p1.u.x = relu2(p1.u.x); p1.u.y = relu2(p1.u.y);
        p1.u.z = relu2(p1.u.z); p1.u.w = relu2(p1.u.w);

        float4v acc[4];
#pragma unroll
        for (int t = 0; t < 4; ++t)
            acc[t] = (float4v){binit[t * 4], binit[t * 4 + 1],
                               binit[t * 4 + 2], binit[t * 4 + 3]};
#pragma unroll
        for (int t = 0; t < 4; ++t)
            acc[t] = __builtin_amdgcn_mfma_f32_16x16x32_bf16(wf[t][0], p0.s, acc[t], 0, 0, 0);
#pragma unroll
        for (int t = 0; t < 4; ++t)
            acc[t] = __builtin_amdgcn_mfma_f32_16x16x32_bf16(wf[t][1], p1.s, acc[t], 0, 0, 0);
#pragma unroll
        for (int t = 0; t < 4; ++t)
            acc[t] = __builtin_amdgcn_mfma_f32_16x16x32_bf16(wf[t][2], p2.s, acc[t], 0, 0, 0);
#pragma unroll
        for (int t = 0; t < 4; ++t)
            acc[t] = __builtin_amdgcn_mfma_f32_16x16x32_bf16(wf[t][3], p3.s, acc[t], 0, 0, 0);

        // residual (raw h) + relu -> LDS transpose tile
        const int pl = wave * 16 + col;
#pragma unroll
        for (int t = 0; t < 4; ++t) {
            const uint2 rd = *(const uint2*)(hT + (g0 + col) * 64 + t * 16 + quad * 4);
            const int o = t * 16 + quad * 4;
            ts[o + 0][pl] = fmaxf(acc[t][0] + blo(rd.x), 0.f);
            ts[o + 1][pl] = fmaxf(acc[t][1] + bhi(rd.x), 0.f);
            ts[o + 2][pl] = fmaxf(acc[t][2] + blo(rd.y), 0.f);
            ts[o + 3][pl] = fmaxf(acc[t][3] + bhi(rd.y), 0.f);
        }
        __syncthreads();

        // coalesced store: o = wave*16+r rows, n = lane
        const int g2  = gb + lane;
        const int bo2 = batch_base(g2);
        const int b2  = (g2 >= 3 * NN) ? 3 : (g2 >= 2 * NN) ? 2 : (g2 >= NN) ? 1 : 0;
        const int n2  = g2 - bo2;
#pragma unroll
        for (int r = 0; r < 16; ++r) {
            const int o = wave * 16 + r;
            out[((size_t)b2 * 64 + o) * NN + n2] = ts[o][lane];
        }
        __syncthreads();
    }
}

// ---------------------------------------------------------------------------
// Workspace (bytes), total ~153.7 MB:
//   [0, 51.2M)        xT   (xpose -> gatherx, gemm1)
//   [51.2M, 102.4M)   SX   (gatherx -> gemm1), then SH (gatherh -> gemm2)
//   [102.4M, 153.6M)  hT   (gemm1 -> gatherh, gemm2)
//   153,600,000 stats[128] f32;  153,600,512 ab[128] f32;
//   153,601,024 Wf0 bf16[8192];  153,617,408 Wf1 bf16[8192];
//   153,633,792 bias[64] f32    (end 153,634,048)
// ---------------------------------------------------------------------------
extern "C" void kernel_launch(void* const* d_in, const int* in_sizes, int n_in,
                              void* d_out, int out_size, void* d_ws, size_t ws_size,
                              hipStream_t stream)
{
    const float* x     = (const float*)d_in[0];
    const int*   neigh = (const int*)d_in[1];
    const float* W0    = (const float*)d_in[2];
    const float* W1    = (const float*)d_in[3];
    const float* gamma = (const float*)d_in[4];
    const float* beta  = (const float*)d_in[5];
    float* out = (float*)d_out;

    char* ws = (char*)d_ws;
    ushort* xT    = (ushort*)(ws + 0);
    ushort* SX    = (ushort*)(ws + 51200000);
    ushort* SH    = SX;
    ushort* hT    = (ushort*)(ws + 102400000);
    float*  stats = (float*)(ws + 153600000);
    float*  ab    = (float*)(ws + 153600512);
    ushort* Wf0   = (ushort*)(ws + 153601024);
    ushort* Wf1   = (ushort*)(ws + 153617408);
    float*  bias  = (float*)(ws + 153633792);

    hipMemsetAsync(stats, 0, 512, stream);
    wprep0_k<<<dim3(32), dim3(256), 0, stream>>>(W0, Wf0);
    xpose_k<<<dim3((NN + 63) / 64, BB), dim3(256), 0, stream>>>(x, xT);
    gatherx_k<<<dim3(3125), dim3(256), 0, stream>>>(xT, neigh, SX);
    gemm1_k<<<dim3(625), dim3(256), 0, stream>>>(xT, SX, Wf0, hT, stats);
    bnA_k<<<dim3(1), dim3(64), 0, stream>>>(stats, gamma, beta, ab);
    bnB_k<<<dim3(33), dim3(256), 0, stream>>>(ab, W1, Wf1, bias);
    gatherh_k<<<dim3(3125), dim3(256), 0, stream>>>(hT, neigh, SH);
    gemm2_k<<<dim3(625), dim3(256), 0, stream>>>(hT, SH, Wf1, bias, out);
}

// Round 9
// 358.164 us; speedup vs baseline: 1.0366x; 1.0366x over previous
//
#include <hip/hip_runtime.h>
#include <hip/hip_bf16.h>

// Problem constants: B=4, C_IN=C_OUT=64, N=100000, K=6
#define BB   4
#define NN   100000
#define TOT  (BB * NN)          // 400000
#define KK   6
#define EPSV 1e-5f

using bf16   = __hip_bfloat16;
using ushort = unsigned short;
using uint32 = unsigned int;
typedef __attribute__((ext_vector_type(8))) short  short8;   // 8 bf16 = 4 VGPRs
typedef __attribute__((ext_vector_type(4))) float  float4v;  // MFMA C/D

union U4S8 { uint4 u; short8 s; };

__device__ __forceinline__ unsigned f2bu(float f) {          // f32 -> raw bf16 RNE
    union { bf16 h; ushort u; } c; c.h = __float2bfloat16(f); return c.u;
}
__device__ __forceinline__ unsigned pk(float a, float b) {
    return f2bu(a) | (f2bu(b) << 16);
}
__device__ __forceinline__ float blo(unsigned x) {           // low bf16 -> f32
    union { unsigned u; float f; } c; c.u = x << 16; return c.f;
}
__device__ __forceinline__ float bhi(unsigned x) {           // high bf16 -> f32
    union { unsigned u; float f; } c; c.u = x & 0xFFFF0000u; return c.f;
}
__device__ __forceinline__ unsigned relu2(unsigned x) {      // relu on packed 2xbf16
    unsigned lo = (unsigned)(((int)(x << 16)) >> 31) & 0x0000FFFFu;
    unsigned hi = ((unsigned)(((int)x) >> 31)) << 16;
    return x & ~(lo | hi);
}
__device__ __forceinline__ int batch_base(int g) {           // (g/NN)*NN via compares
    return (g >= 3 * NN) ? 3 * NN : (g >= 2 * NN) ? 2 * NN : (g >= NN) ? NN : 0;
}

#define ACC8(v)  { h[0]+=blo(v.x); h[1]+=bhi(v.x); h[2]+=blo(v.y); h[3]+=bhi(v.y); \
                   h[4]+=blo(v.z); h[5]+=bhi(v.z); h[6]+=blo(v.w); h[7]+=bhi(v.w); }
#define ACCR8(v) { unsigned _q0=relu2(v.x),_q1=relu2(v.y),_q2=relu2(v.z),_q3=relu2(v.w); \
                   h[0]+=blo(_q0); h[1]+=bhi(_q0); h[2]+=blo(_q1); h[3]+=bhi(_q1); \
                   h[4]+=blo(_q2); h[5]+=bhi(_q2); h[6]+=blo(_q3); h[7]+=bhi(_q3); }

// ---------------------------------------------------------------------------
// wprep0: swizzle stacked weights [We | Wo] (K=128) into MFMA A-role frags.
// ---------------------------------------------------------------------------
__global__ void wprep0_k(const float* __restrict__ W0, ushort* __restrict__ Wf0)
{
    int L = blockIdx.x * 256 + threadIdx.x;        // 8192
    if (L < 8192) {
        int i = L & 7, lane = (L >> 3) & 63, r = L >> 9;   // r = t*4+ks
        int t = r >> 2, ks = r & 3;
        int o = t * 16 + (lane & 15);
        int c = ks * 32 + (lane >> 4) * 8 + i;             // stacked 0..127
        Wf0[L] = f2bu(W0[o * 128 + (c & 63) * 2 + (c >> 6)]);
    }
}

// ---------------------------------------------------------------------------
// xpose: x [B,C,N] f32 -> xT [B,N,C] bf16 (point-major 128-B rows).
// ---------------------------------------------------------------------------
__global__ __launch_bounds__(256) void xpose_k(const float* __restrict__ x,
                                               ushort* __restrict__ xT)
{
    __shared__ uint32 tileP[64][36];   // [point][packed ch-pair], pad to 36
    const int b  = blockIdx.y;
    const int n0 = blockIdx.x * 64;
    const int tx = threadIdx.x & 63;
    const int ty = threadIdx.x >> 6;
    const float* xb = x + (size_t)b * 64 * NN;
    const int n = n0 + tx;
    const bool valid = (n < NN);
#pragma unroll
    for (int cc = 0; cc < 64; cc += 8) {
        const int c = cc + ty * 2;                 // even channel
        float a0 = valid ? xb[(size_t)c * NN + n] : 0.f;
        float a1 = valid ? xb[(size_t)(c + 1) * NN + n] : 0.f;
        tileP[tx][c >> 1] = pk(a0, a1);
    }
    __syncthreads();
    const int s  = threadIdx.x & 7;
    const int p0 = threadIdx.x >> 3;               // 0..31
#pragma unroll
    for (int t = 0; t < 2; ++t) {
        const int p  = p0 + t * 32;
        const int n2 = n0 + p;
        if (n2 < NN) {
            uint4 v = *(const uint4*)(&tileP[p][s * 4]);
            *(uint4*)(xT + ((size_t)b * NN + n2) * 64 + s * 8) = v;
        }
    }
}

// ---------------------------------------------------------------------------
// GEMM1 (K=128, FUSED GATHER): h[g] = [xT[g] ; sum_k xT[nb_k]] · [We;Wo].
// Each lane (col=point, quad) gathers its own 12 uint4 chunks (6 neighbors x
// 2 k-chunks), f32-sums, packs to the MFMA A-fragment directly — SX never
// materialized (saves 102.4 MB round-trip). BN stats fused as before.
// 1250 blocks x 4 waves x 5 tiles = 25000 tiles.
// ---------------------------------------------------------------------------
__global__ __launch_bounds__(256, 2) void gemm1_k(
    const ushort* __restrict__ xT, const int* __restrict__ neigh,
    const ushort* __restrict__ Wf, ushort* __restrict__ hT,
    float* __restrict__ stats)
{
    __shared__ float red[4][128];
    const int wave = threadIdx.x >> 6;
    const int lane = threadIdx.x & 63;
    const int col  = lane & 15;
    const int quad = lane >> 4;
    const int co   = quad * 8;                     // chunk offset (ushorts)

    short8 wf[4][4];
#pragma unroll
    for (int t = 0; t < 4; ++t)
#pragma unroll
        for (int ks = 0; ks < 4; ++ks)
            wf[t][ks] = *(const short8*)(Wf + ((t * 4 + ks) * 64 + lane) * 8);

    float sA[16], sB[16];
#pragma unroll
    for (int j = 0; j < 16; ++j) { sA[j] = 0.f; sB[j] = 0.f; }

    const int wid = blockIdx.x * 4 + wave;         // 5000 waves, 5 tiles each
    for (int i5 = 0; i5 < 5; ++i5) {
        const int tile = wid * 5 + i5;
        const size_t g0 = (size_t)tile * 16;
        const int gme  = (int)g0 + col;            // this lane's point
        const int bo   = batch_base(gme);
        const int* np  = neigh + (size_t)gme * 6;
        const uint2 i01 = *(const uint2*)(np);
        const uint2 i23 = *(const uint2*)(np + 2);
        const uint2 i45 = *(const uint2*)(np + 4);
        const ushort* xb0 = xT + (size_t)bo * 64;

        // center chunks (coalesced across the wave)
        const ushort* xr = xT + (size_t)gme * 64 + co;
        U4S8 c0, c1;
        c0.u = *(const uint4*)(xr);
        c1.u = *(const uint4*)(xr + 32);

        // 12 gathered chunks: 6 rows x (k-chunk A at +co, k-chunk B at +32+co)
        uint4 ga0 = *(const uint4*)(xb0 + (size_t)(int)i01.x * 64 + co);
        uint4 ga1 = *(const uint4*)(xb0 + (size_t)(int)i01.y * 64 + co);
        uint4 ga2 = *(const uint4*)(xb0 + (size_t)(int)i23.x * 64 + co);
        uint4 ga3 = *(const uint4*)(xb0 + (size_t)(int)i23.y * 64 + co);
        uint4 ga4 = *(const uint4*)(xb0 + (size_t)(int)i45.x * 64 + co);
        uint4 ga5 = *(const uint4*)(xb0 + (size_t)(int)i45.y * 64 + co);
        uint4 gb0 = *(const uint4*)(xb0 + (size_t)(int)i01.x * 64 + 32 + co);
        uint4 gb1 = *(const uint4*)(xb0 + (size_t)(int)i01.y * 64 + 32 + co);
        uint4 gb2 = *(const uint4*)(xb0 + (size_t)(int)i23.x * 64 + 32 + co);
        uint4 gb3 = *(const uint4*)(xb0 + (size_t)(int)i23.y * 64 + 32 + co);
        uint4 gb4 = *(const uint4*)(xb0 + (size_t)(int)i45.x * 64 + 32 + co);
        uint4 gb5 = *(const uint4*)(xb0 + (size_t)(int)i45.y * 64 + 32 + co);

        float h[8] = {0, 0, 0, 0, 0, 0, 0, 0};
        ACC8(ga0) ACC8(ga1) ACC8(ga2) ACC8(ga3) ACC8(ga4) ACC8(ga5)
        U4S8 p2;
        p2.u.x = pk(h[0], h[1]); p2.u.y = pk(h[2], h[3]);
        p2.u.z = pk(h[4], h[5]); p2.u.w = pk(h[6], h[7]);
#pragma unroll
        for (int j = 0; j < 8; ++j) h[j] = 0.f;
        ACC8(gb0) ACC8(gb1) ACC8(gb2) ACC8(gb3) ACC8(gb4) ACC8(gb5)
        U4S8 p3;
        p3.u.x = pk(h[0], h[1]); p3.u.y = pk(h[2], h[3]);
        p3.u.z = pk(h[4], h[5]); p3.u.w = pk(h[6], h[7]);

        float4v acc[4];
#pragma unroll
        for (int t = 0; t < 4; ++t) acc[t] = (float4v){0.f, 0.f, 0.f, 0.f};
#pragma unroll
        for (int t = 0; t < 4; ++t)
            acc[t] = __builtin_amdgcn_mfma_f32_16x16x32_bf16(wf[t][0], c0.s, acc[t], 0, 0, 0);
#pragma unroll
        for (int t = 0; t < 4; ++t)
            acc[t] = __builtin_amdgcn_mfma_f32_16x16x32_bf16(wf[t][1], c1.s, acc[t], 0, 0, 0);
#pragma unroll
        for (int t = 0; t < 4; ++t)
            acc[t] = __builtin_amdgcn_mfma_f32_16x16x32_bf16(wf[t][2], p2.s, acc[t], 0, 0, 0);
#pragma unroll
        for (int t = 0; t < 4; ++t)
            acc[t] = __builtin_amdgcn_mfma_f32_16x16x32_bf16(wf[t][3], p3.s, acc[t], 0, 0, 0);

        // store raw h (bf16) + accumulate relu stats from f32 acc
#pragma unroll
        for (int t = 0; t < 4; ++t) {
            uint2 d;
            d.x = pk(acc[t][0], acc[t][1]);
            d.y = pk(acc[t][2], acc[t][3]);
            *(uint2*)(hT + (size_t)gme * 64 + t * 16 + quad * 4) = d;
#pragma unroll
            for (int r = 0; r < 4; ++r) {
                float rv = fmaxf(acc[t][r], 0.f);
                sA[t * 4 + r] += rv;
                sB[t * 4 + r]  = fmaf(rv, rv, sB[t * 4 + r]);
            }
        }
    }

    // reduce over the 16 point-cols (lane bits 0..3)
#pragma unroll
    for (int d = 1; d < 16; d <<= 1)
#pragma unroll
        for (int j = 0; j < 16; ++j) {
            sA[j] += __shfl_xor(sA[j], d);
            sB[j] += __shfl_xor(sB[j], d);
        }
    if (col == 0) {
#pragma unroll
        for (int t = 0; t < 4; ++t)
#pragma unroll
            for (int r = 0; r < 4; ++r) {
                const int o = t * 16 + quad * 4 + r;
                red[wave][o]      = sA[t * 4 + r];
                red[wave][64 + o] = sB[t * 4 + r];
            }
    }
    __syncthreads();
    if (threadIdx.x < 128) {
        float v = red[0][threadIdx.x] + red[1][threadIdx.x]
                + red[2][threadIdx.x] + red[3][threadIdx.x];
        atomicAdd(&stats[threadIdx.x], v);   // 1250 adds per address total
    }
}

// ---------------------------------------------------------------------------
// bnA: stats -> per-channel affine  rhat = a*relu(h) + b.   (1 block, ~2 us)
// ---------------------------------------------------------------------------
__global__ void bnA_k(const float* __restrict__ stats, const float* __restrict__ gamma,
                      const float* __restrict__ beta, float* __restrict__ ab)
{
    const int o = threadIdx.x;
    if (o < 64) {
        const float inv = 1.f / (float)TOT;
        float mean = stats[o] * inv;
        float var  = stats[64 + o] * inv - mean * mean;   // biased var (jnp.var)
        float a    = gamma[o] * rsqrtf(var + EPSV);
        ab[o]      = a;
        ab[64 + o] = fmaf(-a, mean, beta[o]);
    }
}

// ---------------------------------------------------------------------------
// bnB: Wf1 = swizzled stacked [a⊙We1 | a⊙Wo1] (K=128, blocks 0..31) +
// bias[o] = sum_c b_c*(We1[o][c] + 6*Wo1[o][c])  (block 32).
// ---------------------------------------------------------------------------
__global__ __launch_bounds__(256) void bnB_k(
    const float* __restrict__ ab, const float* __restrict__ W1,
    ushort* __restrict__ Wf1, float* __restrict__ bias)
{
    if (blockIdx.x < 32) {
        int L = blockIdx.x * 256 + threadIdx.x;   // 8192
        int i = L & 7, lane = (L >> 3) & 63, r = L >> 9;
        int t = r >> 2, ks = r & 3;
        int o = t * 16 + (lane & 15);
        int c = ks * 32 + (lane >> 4) * 8 + i;
        int cc = c & 63;
        Wf1[L] = f2bu(ab[cc] * W1[o * 128 + cc * 2 + (c >> 6)]);
    } else if (threadIdx.x < 64) {
        const int o = threadIdx.x;
        float s = 0.f;
#pragma unroll
        for (int c = 0; c < 64; ++c)
            s += ab[64 + c] * (W1[o * 128 + c * 2] + 6.f * W1[o * 128 + c * 2 + 1]);
        bias[o] = s;
    }
}

// ---------------------------------------------------------------------------
// GEMM2 (K=128, FUSED GATHER): out = relu([relu(h) ; sum_k relu(h[nb_k])]·Wf1
//                                          + bias + h).
// Same per-lane 12-uint4 gather with relu2 applied per gathered chunk; SH
// never materialized. Epilogue: residual add + relu + LDS transpose +
// coalesced f32 store. 1250 blocks x 5 iters x 64 points.
// ---------------------------------------------------------------------------
__global__ __launch_bounds__(256, 2) void gemm2_k(
    const ushort* __restrict__ hT, const int* __restrict__ neigh,
    const ushort* __restrict__ Wf, const float* __restrict__ bias,
    float* __restrict__ out)
{
    __shared__ float ts[64][65];
    const int wave = threadIdx.x >> 6;
    const int lane = threadIdx.x & 63;
    const int col  = lane & 15;
    const int quad = lane >> 4;
    const int co   = quad * 8;

    short8 wf[4][4];
#pragma unroll
    for (int t = 0; t < 4; ++t)
#pragma unroll
        for (int ks = 0; ks < 4; ++ks)
            wf[t][ks] = *(const short8*)(Wf + ((t * 4 + ks) * 64 + lane) * 8);

    float binit[16];
#pragma unroll
    for (int t = 0; t < 4; ++t)
#pragma unroll
        for (int r = 0; r < 4; ++r)
            binit[t * 4 + r] = bias[t * 16 + quad * 4 + r];

    for (int it = 0; it < 5; ++it) {
        const int gb = (blockIdx.x * 5 + it) * 64;        // 64 consecutive points
        const int gme = gb + wave * 16 + col;             // this lane's point
        const int bo  = batch_base(gme);
        const int* np = neigh + (size_t)gme * 6;
        const uint2 i01 = *(const uint2*)(np);
        const uint2 i23 = *(const uint2*)(np + 2);
        const uint2 i45 = *(const uint2*)(np + 4);
        const ushort* hb0 = hT + (size_t)bo * 64;

        // center chunks + relu
        const ushort* hr = hT + (size_t)gme * 64 + co;
        U4S8 c0, c1;
        c0.u = *(const uint4*)(hr);
        c1.u = *(const uint4*)(hr + 32);
        c0.u.x = relu2(c0.u.x); c0.u.y = relu2(c0.u.y);
        c0.u.z = relu2(c0.u.z); c0.u.w = relu2(c0.u.w);
        c1.u.x = relu2(c1.u.x); c1.u.y = relu2(c1.u.y);
        c1.u.z = relu2(c1.u.z); c1.u.w = relu2(c1.u.w);

        uint4 ga0 = *(const uint4*)(hb0 + (size_t)(int)i01.x * 64 + co);
        uint4 ga1 = *(const uint4*)(hb0 + (size_t)(int)i01.y * 64 + co);
        uint4 ga2 = *(const uint4*)(hb0 + (size_t)(int)i23.x * 64 + co);
        uint4 ga3 = *(const uint4*)(hb0 + (size_t)(int)i23.y * 64 + co);
        uint4 ga4 = *(const uint4*)(hb0 + (size_t)(int)i45.x * 64 + co);
        uint4 ga5 = *(const uint4*)(hb0 + (size_t)(int)i45.y * 64 + co);
        uint4 gb0 = *(const uint4*)(hb0 + (size_t)(int)i01.x * 64 + 32 + co);
        uint4 gb1 = *(const uint4*)(hb0 + (size_t)(int)i01.y * 64 + 32 + co);
        uint4 gb2 = *(const uint4*)(hb0 + (size_t)(int)i23.x * 64 + 32 + co);
        uint4 gb3 = *(const uint4*)(hb0 + (size_t)(int)i23.y * 64 + 32 + co);
        uint4 gb4 = *(const uint4*)(hb0 + (size_t)(int)i45.x * 64 + 32 + co);
        uint4 gb5 = *(const uint4*)(hb0 + (size_t)(int)i45.y * 64 + 32 + co);

        float h[8] = {0, 0, 0, 0, 0, 0, 0, 0};
        ACCR8(ga0) ACCR8(ga1) ACCR8(ga2) ACCR8(ga3) ACCR8(ga4) ACCR8(ga5)
        U4S8 p2;
        p2.u.x = pk(h[0], h[1]); p2.u.y = pk(h[2], h[3]);
        p2.u.z = pk(h[4], h[5]); p2.u.w = pk(h[6], h[7]);
#pragma unroll
        for (int j = 0; j < 8; ++j) h[j] = 0.f;
        ACCR8(gb0) ACCR8(gb1) ACCR8(gb2) ACCR8(gb3) ACCR8(gb4) ACCR8(gb5)
        U4S8 p3;
        p3.u.x = pk(h[0], h[1]); p3.u.y = pk(h[2], h[3]);
        p3.u.z = pk(h[4], h[5]); p3.u.w = pk(h[6], h[7]);

        float4v acc[4];
#pragma unroll
        for (int t = 0; t < 4; ++t)
            acc[t] = (float4v){binit[t * 4], binit[t * 4 + 1],
                               binit[t * 4 + 2], binit[t * 4 + 3]};
#pragma unroll
        for (int t = 0; t < 4; ++t)
            acc[t] = __builtin_amdgcn_mfma_f32_16x16x32_bf16(wf[t][0], c0.s, acc[t], 0, 0, 0);
#pragma unroll
        for (int t = 0; t < 4; ++t)
            acc[t] = __builtin_amdgcn_mfma_f32_16x16x32_bf16(wf[t][1], c1.s, acc[t], 0, 0, 0);
#pragma unroll
        for (int t = 0; t < 4; ++t)
            acc[t] = __builtin_amdgcn_mfma_f32_16x16x32_bf16(wf[t][2], p2.s, acc[t], 0, 0, 0);
#pragma unroll
        for (int t = 0; t < 4; ++t)
            acc[t] = __builtin_amdgcn_mfma_f32_16x16x32_bf16(wf[t][3], p3.s, acc[t], 0, 0, 0);

        // residual (raw h) + relu -> LDS transpose tile
        const int pl = wave * 16 + col;
#pragma unroll
        for (int t = 0; t < 4; ++t) {
            const uint2 rd = *(const uint2*)(hT + (size_t)gme * 64 + t * 16 + quad * 4);
            const int o = t * 16 + quad * 4;
            ts[o + 0][pl] = fmaxf(acc[t][0] + blo(rd.x), 0.f);
            ts[o + 1][pl] = fmaxf(acc[t][1] + bhi(rd.x), 0.f);
            ts[o + 2][pl] = fmaxf(acc[t][2] + blo(rd.y), 0.f);
            ts[o + 3][pl] = fmaxf(acc[t][3] + bhi(rd.y), 0.f);
        }
        __syncthreads();

        // coalesced store: o = wave*16+r rows, n = lane
        const int g2  = gb + lane;
        const int bo2 = batch_base(g2);
        const int bb2 = (g2 >= 3 * NN) ? 3 : (g2 >= 2 * NN) ? 2 : (g2 >= NN) ? 1 : 0;
        const int n2  = g2 - bo2;
#pragma unroll
        for (int r = 0; r < 16; ++r) {
            const int o = wave * 16 + r;
            out[((size_t)bb2 * 64 + o) * NN + n2] = ts[o][lane];
        }
        __syncthreads();
    }
}

// ---------------------------------------------------------------------------
// Workspace (bytes), total ~153.7 MB (SX/SH slot now unused; layout kept):
//   [0, 51.2M)        xT   (xpose -> gemm1)
//   [51.2M, 102.4M)   (unused)
//   [102.4M, 153.6M)  hT   (gemm1 -> gemm2)
//   153,600,000 stats[128] f32;  153,600,512 ab[128] f32;
//   153,601,024 Wf0 bf16[8192];  153,617,408 Wf1 bf16[8192];
//   153,633,792 bias[64] f32    (end 153,634,048)
// ---------------------------------------------------------------------------
extern "C" void kernel_launch(void* const* d_in, const int* in_sizes, int n_in,
                              void* d_out, int out_size, void* d_ws, size_t ws_size,
                              hipStream_t stream)
{
    const float* x     = (const float*)d_in[0];
    const int*   neigh = (const int*)d_in[1];
    const float* W0    = (const float*)d_in[2];
    const float* W1    = (const float*)d_in[3];
    const float* gamma = (const float*)d_in[4];
    const float* beta  = (const float*)d_in[5];
    float* out = (float*)d_out;

    char* ws = (char*)d_ws;
    ushort* xT    = (ushort*)(ws + 0);
    ushort* hT    = (ushort*)(ws + 102400000);
    float*  stats = (float*)(ws + 153600000);
    float*  ab    = (float*)(ws + 153600512);
    ushort* Wf0   = (ushort*)(ws + 153601024);
    ushort* Wf1   = (ushort*)(ws + 153617408);
    float*  bias  = (float*)(ws + 153633792);

    hipMemsetAsync(stats, 0, 512, stream);
    wprep0_k<<<dim3(32), dim3(256), 0, stream>>>(W0, Wf0);
    xpose_k<<<dim3((NN + 63) / 64, BB), dim3(256), 0, stream>>>(x, xT);
    gemm1_k<<<dim3(1250), dim3(256), 0, stream>>>(xT, neigh, Wf0, hT, stats);
    bnA_k<<<dim3(1), dim3(64), 0, stream>>>(stats, gamma, beta, ab);
    bnB_k<<<dim3(33), dim3(256), 0, stream>>>(ab, W1, Wf1, bias);
    gemm2_k<<<dim3(1250), dim3(256), 0, stream>>>(hT, neigh, Wf1, bias, out);
}